// Round 4
// baseline (140.823 us; speedup 1.0000x reference)
//
#include <hip/hip_runtime.h>
#include <math.h>

// SinkhornM round 6:
//  - Round-3 lean packed-f32x2 MLP, but weights delivered from LDS
//    (round-0's mechanism): float4 ds_read broadcasts, no rolling-SGPR
//    s_load waits threaded through the MLP.
//  - Sinkhorn tails of the two rows INTERLEAVED (2x ILP on the serial
//    rcp chains). Spill-safe: epilogue needs only C (A_ij = u_i*C_ij*w_j),
//    so `a` and B die early; launch_bounds(256,4) caps VGPR at 128.
//  - Folded Sinkhorn (round-3-verified): B_ij=a_ij*rm_i, C_ij=a_ij*cm_j;
//    z=rcp(t); q=B^T z; w=rcp(q); t=C w; final t-update skipped.

#define QLOW  0.02f
#define QSPAN 0.96f
#define L2E   1.44269504088896f

constexpr int R = 2;

typedef __attribute__((ext_vector_type(2))) float f32x2;

__device__ __forceinline__ float frcp(float x) { return __builtin_amdgcn_rcpf(x); }
__device__ __forceinline__ f32x2 pfma(f32x2 a, f32x2 b, f32x2 c) {
    return __builtin_elementwise_fma(a, b, c);
}

__global__ __launch_bounds__(256, 4) void sinkhorn_fused(
    const float* __restrict__ margins,
    const float* __restrict__ W1, const float* __restrict__ b1,
    const float* __restrict__ W2, const float* __restrict__ b2,
    const float* __restrict__ W3, const float* __restrict__ b3,
    float* __restrict__ out, int n)
{
    __shared__ __align__(16) float sW1[256];     // (8,32) row-major
    __shared__ __align__(16) float sW2[512];     // (32,16) row-major
    __shared__ __align__(16) float sW3[16 * 12]; // (16,9) padded to stride 12
    __shared__ __align__(16) float sB1[32];
    __shared__ __align__(16) float sB2[16];
    __shared__ __align__(16) float sB3[12];

    {
        const int t = threadIdx.x;
        sW1[t] = W1[t];
        sW2[t] = W2[t];
        sW2[t + 256] = W2[t + 256];
        if (t < 144) { const int k = t / 9, j = t - 9 * k; sW3[k * 12 + j] = W3[t]; }
        if (t < 32) sB1[t] = b1[t];
        if (t < 16) sB2[t] = b2[t];
        if (t < 9)  sB3[t] = b3[t];
    }
    __syncthreads();

    const float4* __restrict__ sW1q = (const float4*)sW1;  // [k*8 + j4]
    const float4* __restrict__ sW2q = (const float4*)sW2;  // [k*4 + j4]
    const float4* __restrict__ sW3q = (const float4*)sW3;  // [k*3 + {0,1}]

    const int tid  = blockIdx.x * blockDim.x + threadIdx.x;
    const int lane = tid & 63;
    const int base = (tid >> 6) * (64 * R) + lane;  // rows base, base+64

    const float4* __restrict__ m4 = (const float4*)margins;

    float m[R][8];
#pragma unroll
    for (int r = 0; r < R; ++r) {
        const int row = base + 64 * r;
        const float4 a0 = m4[row * 2 + 0];
        const float4 a1 = m4[row * 2 + 1];
        m[r][0] = a0.x; m[r][1] = a0.y; m[r][2] = a0.z; m[r][3] = a0.w;
        m[r][4] = a1.x; m[r][5] = a1.y; m[r][6] = a1.z; m[r][7] = a1.w;
    }

    // ---- layer 1: h1 = relu(m @ W1 + b1), 32 wide = 16 f32x2 pairs ----
    f32x2 h1[R][16];
#pragma unroll
    for (int j = 0; j < 16; ++j) {
        const f32x2 bb = {sB1[2 * j], sB1[2 * j + 1]};
#pragma unroll
        for (int r = 0; r < R; ++r) h1[r][j] = bb;
    }
#pragma unroll
    for (int k = 0; k < 8; ++k) {
        f32x2 mk[R];
#pragma unroll
        for (int r = 0; r < R; ++r) { mk[r].x = m[r][k]; mk[r].y = m[r][k]; }
#pragma unroll
        for (int j4 = 0; j4 < 8; ++j4) {
            const float4 w = sW1q[k * 8 + j4];
            const f32x2 wa = {w.x, w.y};
            const f32x2 wb = {w.z, w.w};
#pragma unroll
            for (int r = 0; r < R; ++r) {
                h1[r][2 * j4 + 0] = pfma(mk[r], wa, h1[r][2 * j4 + 0]);
                h1[r][2 * j4 + 1] = pfma(mk[r], wb, h1[r][2 * j4 + 1]);
            }
        }
    }
    const f32x2 zero2 = {0.0f, 0.0f};
#pragma unroll
    for (int j = 0; j < 16; ++j)
#pragma unroll
        for (int r = 0; r < R; ++r)
            h1[r][j] = __builtin_elementwise_max(h1[r][j], zero2);

    // ---- layer 2: h2 = relu(h1 @ W2 + b2), 16 wide = 8 pairs ----
    f32x2 h2[R][8];
#pragma unroll
    for (int j = 0; j < 8; ++j) {
        const f32x2 bb = {sB2[2 * j], sB2[2 * j + 1]};
#pragma unroll
        for (int r = 0; r < R; ++r) h2[r][j] = bb;
    }
#pragma unroll
    for (int k = 0; k < 32; ++k) {
        f32x2 hk[R];
#pragma unroll
        for (int r = 0; r < R; ++r) {
            const float s = (k & 1) ? h1[r][k >> 1].y : h1[r][k >> 1].x;
            hk[r].x = s; hk[r].y = s;
        }
#pragma unroll
        for (int j4 = 0; j4 < 4; ++j4) {
            const float4 w = sW2q[k * 4 + j4];
            const f32x2 wa = {w.x, w.y};
            const f32x2 wb = {w.z, w.w};
#pragma unroll
            for (int r = 0; r < R; ++r) {
                h2[r][2 * j4 + 0] = pfma(hk[r], wa, h2[r][2 * j4 + 0]);
                h2[r][2 * j4 + 1] = pfma(hk[r], wb, h2[r][2 * j4 + 1]);
            }
        }
    }
#pragma unroll
    for (int j = 0; j < 8; ++j)
#pragma unroll
        for (int r = 0; r < R; ++r)
            h2[r][j] = __builtin_elementwise_max(h2[r][j], zero2);

    // ---- layer 3: p = h2 @ W3 + b3, 9 wide = 4 pairs + 1 scalar ----
    f32x2 p01[R], p23[R], p45[R], p67[R];
    float p8[R];
    {
        const f32x2 b01 = {sB3[0], sB3[1]};
        const f32x2 b23 = {sB3[2], sB3[3]};
        const f32x2 b45 = {sB3[4], sB3[5]};
        const f32x2 b67 = {sB3[6], sB3[7]};
        const float b8  = sB3[8];
#pragma unroll
        for (int r = 0; r < R; ++r) {
            p01[r] = b01; p23[r] = b23; p45[r] = b45; p67[r] = b67; p8[r] = b8;
        }
    }
#pragma unroll
    for (int k = 0; k < 16; ++k) {
        const float4 wA = sW3q[k * 3 + 0];   // j = 0..3
        const float4 wB = sW3q[k * 3 + 1];   // j = 4..7
        const float w8  = sW3[k * 12 + 8];
        const f32x2 w01 = {wA.x, wA.y};
        const f32x2 w23 = {wA.z, wA.w};
        const f32x2 w45 = {wB.x, wB.y};
        const f32x2 w67 = {wB.z, wB.w};
#pragma unroll
        for (int r = 0; r < R; ++r) {
            const float s = (k & 1) ? h2[r][k >> 1].y : h2[r][k >> 1].x;
            f32x2 hb; hb.x = s; hb.y = s;
            p01[r] = pfma(hb, w01, p01[r]);
            p23[r] = pfma(hb, w23, p23[r]);
            p45[r] = pfma(hb, w45, p45[r]);
            p67[r] = pfma(hb, w67, p67[r]);
            p8[r]  = fmaf(s, w8, p8[r]);
        }
    }

    // ---- tail: both rows' state built, chains interleaved ----
    // Bm[r][3*i+j] = a_ij*rm_i ; Cm[r][3*i+j] = a_ij*cm_j
    float Bm[R][9], Cm[R][9];
    float t0_[R], t1_[R], t2_[R];
    float rm_[R][3];
    float um_[R][2], uf_[R][2];
    float Vv[R];

#pragma unroll
    for (int r = 0; r < R; ++r) {
        const float l0 = p01[r].x * L2E, l1 = p01[r].y * L2E;
        const float l2 = p23[r].x * L2E, l3 = p23[r].y * L2E;

        const float a00 = exp2f(l0), a01 = exp2f(l1);
        const float a10 = exp2f(l2), a11 = exp2f(l3);
        const float h01 = (l0 + l1) * 0.5f, h23 = (l2 + l3) * 0.5f;
        const float a02 = exp2f(h01);
        const float a12 = exp2f(h23);
        const float a20 = exp2f((l0 + l2) * 0.5f);
        const float a21 = exp2f((l1 + l3) * 0.5f);
        const float a22 = exp2f((h01 + h23) * 0.5f);

        const float s4 = fmaf(QSPAN, frcp(1.0f + exp2f(-L2E * p45[r].x)), QLOW);
        const float s5 = fmaf(QSPAN, frcp(1.0f + exp2f(-L2E * p45[r].y)), QLOW);
        const float s6 = fmaf(QSPAN, frcp(1.0f + exp2f(-L2E * p67[r].x)), QLOW);
        const float s7 = fmaf(QSPAN, frcp(1.0f + exp2f(-L2E * p67[r].y)), QLOW);

        const float M0 = m[r][0], M1 = m[r][1], M2 = m[r][2];
        const float F0 = m[r][3], F1 = m[r][4], F2 = m[r][5];

        const float rm0 = M0 * s4, rm1 = M1 * s5, rm2 = M2;
        const float cm0 = F0 * s6, cm1 = F1 * s7, cm2 = F2;
        rm_[r][0] = rm0; rm_[r][1] = rm1; rm_[r][2] = rm2;
        um_[r][0] = fmaf(-s4, M0, M0);
        um_[r][1] = fmaf(-s5, M1, M1);
        uf_[r][0] = fmaf(-s6, F0, F0);
        uf_[r][1] = fmaf(-s7, F1, F1);

        Bm[r][0] = a00 * rm0; Bm[r][1] = a01 * rm0; Bm[r][2] = a02 * rm0;
        Bm[r][3] = a10 * rm1; Bm[r][4] = a11 * rm1; Bm[r][5] = a12 * rm1;
        Bm[r][6] = a20 * rm2; Bm[r][7] = a21 * rm2; Bm[r][8] = a22 * rm2;
        Cm[r][0] = a00 * cm0; Cm[r][1] = a01 * cm1; Cm[r][2] = a02 * cm2;
        Cm[r][3] = a10 * cm0; Cm[r][4] = a11 * cm1; Cm[r][5] = a12 * cm2;
        Cm[r][6] = a20 * cm0; Cm[r][7] = a21 * cm1; Cm[r][8] = a22 * cm2;

        t0_[r] = (a00 + a01) + a02;   // A @ v with v = 1
        t1_[r] = (a10 + a11) + a12;
        t2_[r] = (a20 + a21) + a22;

        Vv[r] = exp2f(p8[r] * L2E);
    }

    float z0_[R], z1_[R], z2_[R], w0_[R], w1_[R], w2_[R];
#pragma unroll
    for (int it = 0; it < 10; ++it) {
#pragma unroll
        for (int r = 0; r < R; ++r) {
            z0_[r] = frcp(t0_[r]);
            z1_[r] = frcp(t1_[r]);
            z2_[r] = frcp(t2_[r]);
        }
#pragma unroll
        for (int r = 0; r < R; ++r) {
            const float q0 = fmaf(Bm[r][6], z2_[r], fmaf(Bm[r][3], z1_[r], Bm[r][0] * z0_[r]));
            const float q1 = fmaf(Bm[r][7], z2_[r], fmaf(Bm[r][4], z1_[r], Bm[r][1] * z0_[r]));
            const float q2 = fmaf(Bm[r][8], z2_[r], fmaf(Bm[r][5], z1_[r], Bm[r][2] * z0_[r]));
            w0_[r] = frcp(q0);
            w1_[r] = frcp(q1);
            w2_[r] = frcp(q2);
        }
        if (it < 9) {
#pragma unroll
            for (int r = 0; r < R; ++r) {
                t0_[r] = fmaf(Cm[r][2], w2_[r], fmaf(Cm[r][1], w1_[r], Cm[r][0] * w0_[r]));
                t1_[r] = fmaf(Cm[r][5], w2_[r], fmaf(Cm[r][4], w1_[r], Cm[r][3] * w0_[r]));
                t2_[r] = fmaf(Cm[r][8], w2_[r], fmaf(Cm[r][7], w1_[r], Cm[r][6] * w0_[r]));
            }
        }
    }

    float4* __restrict__ o4 = (float4*)out;
    float* __restrict__ oV = out + (size_t)n * 16;

#pragma unroll
    for (int r = 0; r < R; ++r) {
        const int row = base + 64 * r;
        const float u0 = rm_[r][0] * z0_[r];
        const float u1 = rm_[r][1] * z1_[r];
        const float u2 = rm_[r][2] * z2_[r];
        const float w0 = w0_[r], w1 = w1_[r], w2 = w2_[r];

        // A_ij = u_i * C_ij * w_j   (since v_j = cm_j * w_j and C_ij = a_ij*cm_j)
        const float A0f = u0 * Cm[r][0] * w0, A1f = u0 * Cm[r][1] * w1, A2f = u0 * Cm[r][2] * w2;
        const float A3f = u1 * Cm[r][3] * w0, A4f = u1 * Cm[r][4] * w1, A5f = u1 * Cm[r][5] * w2;
        const float A6f = u2 * Cm[r][6] * w0, A7f = u2 * Cm[r][7] * w1, A8f = u2 * Cm[r][8] * w2;

        o4[row * 4 + 0] = make_float4(A0f, A1f, A2f, um_[r][0]);
        o4[row * 4 + 1] = make_float4(A3f, A4f, A5f, um_[r][1]);
        o4[row * 4 + 2] = make_float4(A6f, A7f, A8f, 0.0f);
        o4[row * 4 + 3] = make_float4(uf_[r][0], uf_[r][1], 0.0f, 0.0f);
        oV[row] = Vv[r];
    }
}

extern "C" void kernel_launch(void* const* d_in, const int* in_sizes, int n_in,
                              void* d_out, int out_size, void* d_ws, size_t ws_size,
                              hipStream_t stream) {
    const float* margins = (const float*)d_in[0];
    const float* W1 = (const float*)d_in[1];
    const float* b1 = (const float*)d_in[2];
    const float* W2 = (const float*)d_in[3];
    const float* b2 = (const float*)d_in[4];
    const float* W3 = (const float*)d_in[5];
    const float* b3 = (const float*)d_in[6];

    const int n = in_sizes[0] / 8;       // 1,048,576 rows
    const int threads = n / R;
    dim3 block(256), grid(threads / 256);

    sinkhorn_fused<<<grid, block, 0, stream>>>(margins, W1, b1, W2, b2, W3, b3,
                                               (float*)d_out, n);
}

// Round 5
// 136.925 us; speedup vs baseline: 1.0285x; 1.0285x over previous
//
#include <hip/hip_runtime.h>
#include <math.h>

// SinkhornM round 7: LDS weights + lean packed MLP + sequential folded tail, R=1.
//  - Weights staged to LDS once per block (3.7 KB), ds_read float4
//    broadcasts in the MLP: no rolling-SGPR s_waitcnt serialization
//    (R3's stall source), no per-wave s_load duplication (R=1 safe).
//  - MLP on f32x2 output pairs -> v_pk_fma_f32 (R3's lean issue volume).
//  - R=1: one row/thread. Halves per-wave serial rcp-chain length,
//    halves VGPR (~50 -> 8 waves/SIMD capacity), doubles wave count.
//  - Tail: single-row folded Sinkhorn (R3-verified math), sequential --
//    the interleaved/packed variants (R4, R6) both spilled to scratch
//    (WRITE_SIZE tripwire: must stay at ~69632 KB).

#define QLOW  0.02f
#define QSPAN 0.96f
#define L2E   1.44269504088896f

typedef __attribute__((ext_vector_type(2))) float f32x2;

__device__ __forceinline__ float frcp(float x) { return __builtin_amdgcn_rcpf(x); }
__device__ __forceinline__ f32x2 pfma(f32x2 a, f32x2 b, f32x2 c) {
    return __builtin_elementwise_fma(a, b, c);
}

__global__ __launch_bounds__(256) void sinkhorn_fused(
    const float* __restrict__ margins,
    const float* __restrict__ W1, const float* __restrict__ b1,
    const float* __restrict__ W2, const float* __restrict__ b2,
    const float* __restrict__ W3, const float* __restrict__ b3,
    float* __restrict__ out, int n)
{
    __shared__ __align__(16) float sW1[256];     // (8,32) row-major
    __shared__ __align__(16) float sW2[512];     // (32,16) row-major
    __shared__ __align__(16) float sW3[16 * 12]; // (16,9) padded to stride 12
    __shared__ __align__(16) float sB1[32];
    __shared__ __align__(16) float sB2[16];
    __shared__ __align__(16) float sB3[12];

    {
        const int t = threadIdx.x;
        sW1[t] = W1[t];
        sW2[t] = W2[t];
        sW2[t + 256] = W2[t + 256];
        if (t < 144) { const int k = t / 9, j = t - 9 * k; sW3[k * 12 + j] = W3[t]; }
        if (t < 32) sB1[t] = b1[t];
        if (t < 16) sB2[t] = b2[t];
        if (t < 9)  sB3[t] = b3[t];
    }
    __syncthreads();

    const float4* __restrict__ sW1q = (const float4*)sW1;  // [k*8 + j4]
    const float4* __restrict__ sW2q = (const float4*)sW2;  // [k*4 + j4]
    const float4* __restrict__ sW3q = (const float4*)sW3;  // [k*3 + {0,1}]

    const int row = blockIdx.x * blockDim.x + threadIdx.x;  // 1 row per thread

    const float4* __restrict__ m4 = (const float4*)margins;
    const float4 a0 = m4[row * 2 + 0];
    const float4 a1 = m4[row * 2 + 1];
    float m[8];
    m[0] = a0.x; m[1] = a0.y; m[2] = a0.z; m[3] = a0.w;
    m[4] = a1.x; m[5] = a1.y; m[6] = a1.z; m[7] = a1.w;

    // ---- layer 1: h1 = relu(m @ W1 + b1), 32 wide = 16 f32x2 pairs ----
    f32x2 h1[16];
#pragma unroll
    for (int j = 0; j < 16; ++j) { h1[j].x = sB1[2 * j]; h1[j].y = sB1[2 * j + 1]; }
#pragma unroll
    for (int k = 0; k < 8; ++k) {
        f32x2 mk; mk.x = m[k]; mk.y = m[k];
#pragma unroll
        for (int j4 = 0; j4 < 8; ++j4) {
            const float4 w = sW1q[k * 8 + j4];
            const f32x2 wa = {w.x, w.y};
            const f32x2 wb = {w.z, w.w};
            h1[2 * j4 + 0] = pfma(mk, wa, h1[2 * j4 + 0]);
            h1[2 * j4 + 1] = pfma(mk, wb, h1[2 * j4 + 1]);
        }
    }
    const f32x2 zero2 = {0.0f, 0.0f};
#pragma unroll
    for (int j = 0; j < 16; ++j) h1[j] = __builtin_elementwise_max(h1[j], zero2);

    // ---- layer 2: h2 = relu(h1 @ W2 + b2), 16 wide = 8 pairs ----
    f32x2 h2[8];
#pragma unroll
    for (int j = 0; j < 8; ++j) { h2[j].x = sB2[2 * j]; h2[j].y = sB2[2 * j + 1]; }
#pragma unroll
    for (int k = 0; k < 32; ++k) {
        const float s = (k & 1) ? h1[k >> 1].y : h1[k >> 1].x;
        f32x2 hk; hk.x = s; hk.y = s;
#pragma unroll
        for (int j4 = 0; j4 < 4; ++j4) {
            const float4 w = sW2q[k * 4 + j4];
            const f32x2 wa = {w.x, w.y};
            const f32x2 wb = {w.z, w.w};
            h2[2 * j4 + 0] = pfma(hk, wa, h2[2 * j4 + 0]);
            h2[2 * j4 + 1] = pfma(hk, wb, h2[2 * j4 + 1]);
        }
    }
#pragma unroll
    for (int j = 0; j < 8; ++j) h2[j] = __builtin_elementwise_max(h2[j], zero2);

    // ---- layer 3: p = h2 @ W3 + b3, 9 wide = 4 pairs + 1 scalar ----
    f32x2 p01 = {sB3[0], sB3[1]};
    f32x2 p23 = {sB3[2], sB3[3]};
    f32x2 p45 = {sB3[4], sB3[5]};
    f32x2 p67 = {sB3[6], sB3[7]};
    float p8 = sB3[8];
#pragma unroll
    for (int k = 0; k < 16; ++k) {
        const float4 wA = sW3q[k * 3 + 0];   // j = 0..3
        const float4 wB = sW3q[k * 3 + 1];   // j = 4..7
        const float w8  = sW3[k * 12 + 8];
        const float s = (k & 1) ? h2[k >> 1].y : h2[k >> 1].x;
        f32x2 hb; hb.x = s; hb.y = s;
        p01 = pfma(hb, (f32x2){wA.x, wA.y}, p01);
        p23 = pfma(hb, (f32x2){wA.z, wA.w}, p23);
        p45 = pfma(hb, (f32x2){wB.x, wB.y}, p45);
        p67 = pfma(hb, (f32x2){wB.z, wB.w}, p67);
        p8  = fmaf(s, w8, p8);
    }

    // ---- tau in exp2/log2 space ----
    const float l0 = p01.x * L2E, l1 = p01.y * L2E;
    const float l2 = p23.x * L2E, l3 = p23.y * L2E;

    const float a00 = exp2f(l0), a01 = exp2f(l1);
    const float a10 = exp2f(l2), a11 = exp2f(l3);
    const float h01 = (l0 + l1) * 0.5f, h23 = (l2 + l3) * 0.5f;
    const float a02 = exp2f(h01);
    const float a12 = exp2f(h23);
    const float a20 = exp2f((l0 + l2) * 0.5f);
    const float a21 = exp2f((l1 + l3) * 0.5f);
    const float a22 = exp2f((h01 + h23) * 0.5f);

    const float s4 = fmaf(QSPAN, frcp(1.0f + exp2f(-L2E * p45.x)), QLOW);
    const float s5 = fmaf(QSPAN, frcp(1.0f + exp2f(-L2E * p45.y)), QLOW);
    const float s6 = fmaf(QSPAN, frcp(1.0f + exp2f(-L2E * p67.x)), QLOW);
    const float s7 = fmaf(QSPAN, frcp(1.0f + exp2f(-L2E * p67.y)), QLOW);

    const float M0 = m[0], M1 = m[1], M2 = m[2];
    const float F0 = m[3], F1 = m[4], F2 = m[5];

    const float rm0 = M0 * s4, rm1 = M1 * s5, rm2 = M2;
    const float cm0 = F0 * s6, cm1 = F1 * s7, cm2 = F2;
    const float um0 = fmaf(-s4, M0, M0);
    const float um1 = fmaf(-s5, M1, M1);
    const float uf0 = fmaf(-s6, F0, F0);
    const float uf1 = fmaf(-s7, F1, F1);

    // folded iteration matrices: B_ij = a_ij*rm_i, C_ij = a_ij*cm_j
    const float B00 = a00 * rm0, B01 = a01 * rm0, B02 = a02 * rm0;
    const float B10 = a10 * rm1, B11 = a11 * rm1, B12 = a12 * rm1;
    const float B20 = a20 * rm2, B21 = a21 * rm2, B22 = a22 * rm2;
    const float C00 = a00 * cm0, C01 = a01 * cm1, C02 = a02 * cm2;
    const float C10 = a10 * cm0, C11 = a11 * cm1, C12 = a12 * cm2;
    const float C20 = a20 * cm0, C21 = a21 * cm1, C22 = a22 * cm2;

    float t0 = (a00 + a01) + a02;   // A @ v with v = 1
    float t1 = (a10 + a11) + a12;
    float t2 = (a20 + a21) + a22;
    float z0, z1, z2, w0, w1, w2;
#pragma unroll
    for (int it = 0; it < 10; ++it) {
        z0 = frcp(t0); z1 = frcp(t1); z2 = frcp(t2);
        const float q0 = fmaf(B20, z2, fmaf(B10, z1, B00 * z0));
        const float q1 = fmaf(B21, z2, fmaf(B11, z1, B01 * z0));
        const float q2 = fmaf(B22, z2, fmaf(B12, z1, B02 * z0));
        w0 = frcp(q0); w1 = frcp(q1); w2 = frcp(q2);
        if (it < 9) {
            t0 = fmaf(C02, w2, fmaf(C01, w1, C00 * w0));
            t1 = fmaf(C12, w2, fmaf(C11, w1, C10 * w0));
            t2 = fmaf(C22, w2, fmaf(C21, w1, C20 * w0));
        }
    }
    const float u0 = rm0 * z0, u1 = rm1 * z1, u2 = rm2 * z2;

    // A_ij = u_i * C_ij * w_j   (v_j = cm_j*w_j, C_ij = a_ij*cm_j)
    const float A0f = u0 * C00 * w0, A1f = u0 * C01 * w1, A2f = u0 * C02 * w2;
    const float A3f = u1 * C10 * w0, A4f = u1 * C11 * w1, A5f = u1 * C12 * w2;
    const float A6f = u2 * C20 * w0, A7f = u2 * C21 * w1, A8f = u2 * C22 * w2;

    float4* __restrict__ o4 = (float4*)out;
    float* __restrict__ oV = out + (size_t)n * 16;

    o4[row * 4 + 0] = make_float4(A0f, A1f, A2f, um0);
    o4[row * 4 + 1] = make_float4(A3f, A4f, A5f, um1);
    o4[row * 4 + 2] = make_float4(A6f, A7f, A8f, 0.0f);
    o4[row * 4 + 3] = make_float4(uf0, uf1, 0.0f, 0.0f);
    oV[row] = exp2f(p8 * L2E);
}

extern "C" void kernel_launch(void* const* d_in, const int* in_sizes, int n_in,
                              void* d_out, int out_size, void* d_ws, size_t ws_size,
                              hipStream_t stream) {
    const float* margins = (const float*)d_in[0];
    const float* W1 = (const float*)d_in[1];
    const float* b1 = (const float*)d_in[2];
    const float* W2 = (const float*)d_in[3];
    const float* b2 = (const float*)d_in[4];
    const float* W3 = (const float*)d_in[5];
    const float* b3 = (const float*)d_in[6];

    const int n = in_sizes[0] / 8;       // 1,048,576 rows
    dim3 block(256), grid(n / 256);      // 1 row per thread

    sinkhorn_fused<<<grid, block, 0, stream>>>(margins, W1, b1, W2, b2, W3, b3,
                                               (float*)d_out, n);
}

// Round 6
// 128.524 us; speedup vs baseline: 1.0957x; 1.0654x over previous
//
#include <hip/hip_runtime.h>
#include <math.h>

// SinkhornM round 8 = R3 (47.7us: s_load weights, lean packed MLP) with the
// two rows' Sinkhorn chains INTERLEAVED, spill-proofed:
//  - no pre-folded B/C (saves 36 regs): fold rm/cm on the fly
//      z=rcp(t); zp=rm*z; q=A^T zp; w=rcp(q); wp=cm*w; t=A wp
//    (zp==u, wp==v at every step -> exact same math as verified R3 tail)
//  - um/uf recomputed as M-rm / F-cm at the end (no carried regs)
//  - launch_bounds(256,2): allow up to the 128-VGPR/4-wave plateau instead
//    of the 64-reg point the compiler defended with scratch in R6.
// Tripwire: WRITE_SIZE must stay ~69632 KB (spill shows up there, R4/R6).

#define QLOW  0.02f
#define QSPAN 0.96f
#define L2E   1.44269504088896f

constexpr int R = 2;

typedef __attribute__((ext_vector_type(2))) float f32x2;

__device__ __forceinline__ float frcp(float x) { return __builtin_amdgcn_rcpf(x); }
__device__ __forceinline__ f32x2 pfma(f32x2 a, f32x2 b, f32x2 c) {
    return __builtin_elementwise_fma(a, b, c);
}

__global__ __launch_bounds__(256, 2) void sinkhorn_fused(
    const float* __restrict__ margins,
    const float* __restrict__ W1, const float* __restrict__ b1,
    const float* __restrict__ W2, const float* __restrict__ b2,
    const float* __restrict__ W3, const float* __restrict__ b3,
    float* __restrict__ out, int n)
{
    const int tid  = blockIdx.x * blockDim.x + threadIdx.x;
    const int lane = tid & 63;
    const int base = (tid >> 6) * (64 * R) + lane;  // rows base, base+64

    const float4* __restrict__ m4 = (const float4*)margins;

    float m[R][8];
#pragma unroll
    for (int r = 0; r < R; ++r) {
        const int row = base + 64 * r;
        const float4 a0 = m4[row * 2 + 0];
        const float4 a1 = m4[row * 2 + 1];
        m[r][0] = a0.x; m[r][1] = a0.y; m[r][2] = a0.z; m[r][3] = a0.w;
        m[r][4] = a1.x; m[r][5] = a1.y; m[r][6] = a1.z; m[r][7] = a1.w;
    }

    const f32x2* __restrict__ W1v = (const f32x2*)W1;  // (8,32) -> [k][16 pairs]
    const f32x2* __restrict__ W2v = (const f32x2*)W2;  // (32,16) -> [k][8 pairs]
    const f32x2* __restrict__ b1v = (const f32x2*)b1;
    const f32x2* __restrict__ b2v = (const f32x2*)b2;

    // ---- layer 1: h1 = relu(m @ W1 + b1), 32 wide = 16 pairs ----
    f32x2 h1[R][16];
#pragma unroll
    for (int j = 0; j < 16; ++j) {
        const f32x2 bb = b1v[j];
#pragma unroll
        for (int r = 0; r < R; ++r) h1[r][j] = bb;
    }
#pragma unroll
    for (int k = 0; k < 8; ++k) {
        f32x2 mk[R];
#pragma unroll
        for (int r = 0; r < R; ++r) { mk[r].x = m[r][k]; mk[r].y = m[r][k]; }
#pragma unroll
        for (int j = 0; j < 16; ++j) {
            const f32x2 w = W1v[k * 16 + j];
#pragma unroll
            for (int r = 0; r < R; ++r) h1[r][j] = pfma(mk[r], w, h1[r][j]);
        }
    }
    const f32x2 zero2 = {0.0f, 0.0f};
#pragma unroll
    for (int j = 0; j < 16; ++j)
#pragma unroll
        for (int r = 0; r < R; ++r)
            h1[r][j] = __builtin_elementwise_max(h1[r][j], zero2);

    // ---- layer 2: h2 = relu(h1 @ W2 + b2), 16 wide = 8 pairs ----
    f32x2 h2[R][8];
#pragma unroll
    for (int j = 0; j < 8; ++j) {
        const f32x2 bb = b2v[j];
#pragma unroll
        for (int r = 0; r < R; ++r) h2[r][j] = bb;
    }
#pragma unroll
    for (int k = 0; k < 32; ++k) {
        f32x2 hk[R];
#pragma unroll
        for (int r = 0; r < R; ++r) {
            const float s = (k & 1) ? h1[r][k >> 1].y : h1[r][k >> 1].x;
            hk[r].x = s; hk[r].y = s;
        }
#pragma unroll
        for (int j = 0; j < 8; ++j) {
            const f32x2 w = W2v[k * 8 + j];
#pragma unroll
            for (int r = 0; r < R; ++r) h2[r][j] = pfma(hk[r], w, h2[r][j]);
        }
    }
#pragma unroll
    for (int j = 0; j < 8; ++j)
#pragma unroll
        for (int r = 0; r < R; ++r)
            h2[r][j] = __builtin_elementwise_max(h2[r][j], zero2);

    // ---- layer 3: p = h2 @ W3 + b3, 9 wide = 4 pairs + 1 scalar ----
    f32x2 p01[R], p23[R], p45[R], p67[R];
    float p8[R];
    {
        const f32x2 b01 = {b3[0], b3[1]};
        const f32x2 b23 = {b3[2], b3[3]};
        const f32x2 b45 = {b3[4], b3[5]};
        const f32x2 b67 = {b3[6], b3[7]};
        const float b8  = b3[8];
#pragma unroll
        for (int r = 0; r < R; ++r) {
            p01[r] = b01; p23[r] = b23; p45[r] = b45; p67[r] = b67; p8[r] = b8;
        }
    }
#pragma unroll
    for (int k = 0; k < 16; ++k) {
        const f32x2 w01 = {W3[k * 9 + 0], W3[k * 9 + 1]};
        const f32x2 w23 = {W3[k * 9 + 2], W3[k * 9 + 3]};
        const f32x2 w45 = {W3[k * 9 + 4], W3[k * 9 + 5]};
        const f32x2 w67 = {W3[k * 9 + 6], W3[k * 9 + 7]};
        const float w8  = W3[k * 9 + 8];
#pragma unroll
        for (int r = 0; r < R; ++r) {
            const float s = (k & 1) ? h2[r][k >> 1].y : h2[r][k >> 1].x;
            f32x2 hb; hb.x = s; hb.y = s;
            p01[r] = pfma(hb, w01, p01[r]);
            p23[r] = pfma(hb, w23, p23[r]);
            p45[r] = pfma(hb, w45, p45[r]);
            p67[r] = pfma(hb, w67, p67[r]);
            p8[r]  = fmaf(s, w8, p8[r]);
        }
    }

    // ---- per-row tail state (both rows live; minimal set) ----
    float aa[R][9];          // tau matrix
    float rm[R][3], cm[R][3];
    float t0_[R], t1_[R], t2_[R];
    float Vv[R];

#pragma unroll
    for (int r = 0; r < R; ++r) {
        const float l0 = p01[r].x * L2E, l1 = p01[r].y * L2E;
        const float l2 = p23[r].x * L2E, l3 = p23[r].y * L2E;

        const float a00 = exp2f(l0), a01 = exp2f(l1);
        const float a10 = exp2f(l2), a11 = exp2f(l3);
        const float h01 = (l0 + l1) * 0.5f, h23 = (l2 + l3) * 0.5f;
        const float a02 = exp2f(h01);
        const float a12 = exp2f(h23);
        const float a20 = exp2f((l0 + l2) * 0.5f);
        const float a21 = exp2f((l1 + l3) * 0.5f);
        const float a22 = exp2f((h01 + h23) * 0.5f);
        aa[r][0] = a00; aa[r][1] = a01; aa[r][2] = a02;
        aa[r][3] = a10; aa[r][4] = a11; aa[r][5] = a12;
        aa[r][6] = a20; aa[r][7] = a21; aa[r][8] = a22;

        const float s4 = fmaf(QSPAN, frcp(1.0f + exp2f(-L2E * p45[r].x)), QLOW);
        const float s5 = fmaf(QSPAN, frcp(1.0f + exp2f(-L2E * p45[r].y)), QLOW);
        const float s6 = fmaf(QSPAN, frcp(1.0f + exp2f(-L2E * p67[r].x)), QLOW);
        const float s7 = fmaf(QSPAN, frcp(1.0f + exp2f(-L2E * p67[r].y)), QLOW);

        rm[r][0] = m[r][0] * s4; rm[r][1] = m[r][1] * s5; rm[r][2] = m[r][2];
        cm[r][0] = m[r][3] * s6; cm[r][1] = m[r][4] * s7; cm[r][2] = m[r][5];

        t0_[r] = (a00 + a01) + a02;   // A @ v with v = 1
        t1_[r] = (a10 + a11) + a12;
        t2_[r] = (a20 + a21) + a22;

        Vv[r] = exp2f(p8[r] * L2E);
    }

    // ---- interleaved Sinkhorn: zp==u, wp==v throughout ----
    float zp0[R], zp1[R], zp2[R], wp0[R], wp1[R], wp2[R];
#pragma unroll
    for (int it = 0; it < 10; ++it) {
#pragma unroll
        for (int r = 0; r < R; ++r) {
            zp0[r] = rm[r][0] * frcp(t0_[r]);
            zp1[r] = rm[r][1] * frcp(t1_[r]);
            zp2[r] = rm[r][2] * frcp(t2_[r]);
        }
#pragma unroll
        for (int r = 0; r < R; ++r) {
            const float q0 = fmaf(aa[r][6], zp2[r], fmaf(aa[r][3], zp1[r], aa[r][0] * zp0[r]));
            const float q1 = fmaf(aa[r][7], zp2[r], fmaf(aa[r][4], zp1[r], aa[r][1] * zp0[r]));
            const float q2 = fmaf(aa[r][8], zp2[r], fmaf(aa[r][5], zp1[r], aa[r][2] * zp0[r]));
            wp0[r] = cm[r][0] * frcp(q0);
            wp1[r] = cm[r][1] * frcp(q1);
            wp2[r] = cm[r][2] * frcp(q2);
        }
        if (it < 9) {
#pragma unroll
            for (int r = 0; r < R; ++r) {
                t0_[r] = fmaf(aa[r][2], wp2[r], fmaf(aa[r][1], wp1[r], aa[r][0] * wp0[r]));
                t1_[r] = fmaf(aa[r][5], wp2[r], fmaf(aa[r][4], wp1[r], aa[r][3] * wp0[r]));
                t2_[r] = fmaf(aa[r][8], wp2[r], fmaf(aa[r][7], wp1[r], aa[r][6] * wp0[r]));
            }
        }
    }

    float4* __restrict__ o4 = (float4*)out;
    float* __restrict__ oV = out + (size_t)n * 16;

#pragma unroll
    for (int r = 0; r < R; ++r) {
        const int row = base + 64 * r;
        const float u0 = zp0[r], u1 = zp1[r], u2 = zp2[r];
        const float v0 = wp0[r], v1 = wp1[r], v2 = wp2[r];

        const float A0f = u0 * aa[r][0] * v0, A1f = u0 * aa[r][1] * v1, A2f = u0 * aa[r][2] * v2;
        const float A3f = u1 * aa[r][3] * v0, A4f = u1 * aa[r][4] * v1, A5f = u1 * aa[r][5] * v2;
        const float A6f = u2 * aa[r][6] * v0, A7f = u2 * aa[r][7] * v1, A8f = u2 * aa[r][8] * v2;

        const float um0 = m[r][0] - rm[r][0];
        const float um1 = m[r][1] - rm[r][1];
        const float uf0 = m[r][3] - cm[r][0];
        const float uf1 = m[r][4] - cm[r][1];

        o4[row * 4 + 0] = make_float4(A0f, A1f, A2f, um0);
        o4[row * 4 + 1] = make_float4(A3f, A4f, A5f, um1);
        o4[row * 4 + 2] = make_float4(A6f, A7f, A8f, 0.0f);
        o4[row * 4 + 3] = make_float4(uf0, uf1, 0.0f, 0.0f);
        oV[row] = Vv[r];
    }
}

extern "C" void kernel_launch(void* const* d_in, const int* in_sizes, int n_in,
                              void* d_out, int out_size, void* d_ws, size_t ws_size,
                              hipStream_t stream) {
    const float* margins = (const float*)d_in[0];
    const float* W1 = (const float*)d_in[1];
    const float* b1 = (const float*)d_in[2];
    const float* W2 = (const float*)d_in[3];
    const float* b2 = (const float*)d_in[4];
    const float* W3 = (const float*)d_in[5];
    const float* b3 = (const float*)d_in[6];

    const int n = in_sizes[0] / 8;       // 1,048,576 rows
    const int threads = n / R;
    dim3 block(256), grid(threads / 256);

    sinkhorn_fused<<<grid, block, 0, stream>>>(margins, W1, b1, W2, b2, W3, b3,
                                               (float*)d_out, n);
}